// Round 2
// baseline (1101.836 us; speedup 1.0000x reference)
//
#include <hip/hip_runtime.h>

#define EPS_F 0.1f
#define A_F 100.0f
#define NUMNEG_F 10.0f
#define EXP_EPS 1.1051709f   // e^0.1, gate threshold for (-inner + s)

__global__ __launch_bounds__(256) void grp_edge_kernel(
    const float* __restrict__ x,
    const int* __restrict__ u_idx,
    const int* __restrict__ v_idx,
    float* __restrict__ out,   // out[0]=energy, out+1 = grad (N*64)
    int E)
{
    const int lane   = threadIdx.x & 63;
    const int lane16 = lane & 15;          // lane within 16-lane edge group
    const int wave_in_block = threadIdx.x >> 6;
    const int waves_per_block = blockDim.x >> 6;
    const int wave = blockIdx.x * waves_per_block + wave_in_block;
    const int group = (wave << 2) + (lane >> 4);       // global 16-lane group id
    const int ngroups = (gridDim.x * waves_per_block) << 2;

    const float4* __restrict__ x4 = (const float4*)x;  // 16 float4 per row
    float* __restrict__ grad = out + 1;

    // Minkowski J: flip sign of element 0 (lane16==0, component .x)
    const float sign0 = (lane16 == 0) ? -1.0f : 1.0f;

    float eacc = 0.0f;

    for (int e = group; e < E; e += ngroups) {
        const int u = u_idx[e];
        const int v = v_idx[e];
        const float4 xu = x4[u * 16 + lane16];
        const float4 xv = x4[v * 16 + lane16];

        // per-lane partial Minkowski dot (4 elements)
        float p = xu.x * xv.x * sign0;
        p = fmaf(xu.y, xv.y, p);
        p = fmaf(xu.z, xv.z, p);
        p = fmaf(xu.w, xv.w, p);
        // 16-lane butterfly: all 16 lanes end with the full dot
        #pragma unroll
        for (int off = 8; off >= 1; off >>= 1)
            p += __shfl_xor(p, off, 16);

        const float inner = fminf(p, -1.0f - 1e-7f);
        const float s = sqrtf(inner * inner - 1.0f);   // denom = sqrt(inner^2-1)
        const float t = -inner + s;                    // argument of log; dist = log(t)
        if (t < EXP_EPS) {                             // dist < EPS
            const float dist = __logf(t);
            const float delta = EPS_F - dist;
            eacc += delta * delta;                     // same value on all 16 lanes (16x overcount, fixed later)
            const float factor = -(A_F / NUMNEG_F) * delta / (s + 1e-9f);
            float* gu = grad + (size_t)u * 64 + lane16 * 4;
            float* gv = grad + (size_t)v * 64 + lane16 * 4;
            unsafeAtomicAdd(gu + 0, factor * xv.x * sign0);
            unsafeAtomicAdd(gu + 1, factor * xv.y);
            unsafeAtomicAdd(gu + 2, factor * xv.z);
            unsafeAtomicAdd(gu + 3, factor * xv.w);
            unsafeAtomicAdd(gv + 0, factor * xu.x * sign0);
            unsafeAtomicAdd(gv + 1, factor * xu.y);
            unsafeAtomicAdd(gv + 2, factor * xu.z);
            unsafeAtomicAdd(gv + 3, factor * xu.w);
        }
    }

    // energy: every lane of a group accumulated the same delta^2 (16x).
    // Reduce across the full wave, then scale by 0.5*A/NUMNEG/16 = 0.3125.
    #pragma unroll
    for (int off = 32; off >= 1; off >>= 1)
        eacc += __shfl_xor(eacc, off, 64);
    if (lane == 0 && eacc != 0.0f) {
        unsafeAtomicAdd(&out[0], eacc * (0.5f * A_F / NUMNEG_F / 16.0f));
    }
}

extern "C" void kernel_launch(void* const* d_in, const int* in_sizes, int n_in,
                              void* d_out, int out_size, void* d_ws, size_t ws_size,
                              hipStream_t stream) {
    const float* x     = (const float*)d_in[0];
    const int*   u_idx = (const int*)d_in[1];
    const int*   v_idx = (const int*)d_in[2];
    float* out = (float*)d_out;
    const int E = in_sizes[1];

    // d_out is poisoned with 0xAA before every timed launch; zero it (async, capture-safe)
    hipMemsetAsync(d_out, 0, (size_t)out_size * sizeof(float), stream);

    // grid-stride; one 16-lane group per edge, 4 edges per wave
    const int blocks = 4096;  // 65536 groups, ~15 edges each
    grp_edge_kernel<<<blocks, 256, 0, stream>>>(x, u_idx, v_idx, out, E);
}

// Round 3
// 492.679 us; speedup vs baseline: 2.2364x; 2.2364x over previous
//
#include <hip/hip_runtime.h>

#define EPS_F 0.1f
#define A_F 100.0f
#define NUMNEG_F 10.0f
#define EXP_EPS 1.1051709f   // e^0.1; gate: dist<EPS  <=>  (-inner + s) < e^EPS

__global__ __launch_bounds__(256) void grp_edge_kernel(
    const float* __restrict__ x,
    const int* __restrict__ u_idx,
    const int* __restrict__ v_idx,
    float* __restrict__ out,   // out[0]=energy, out+1 = grad (N*64)
    int E)
{
    const int lane = threadIdx.x & 63;
    const int wave_in_block = threadIdx.x >> 6;
    const int waves_per_block = blockDim.x >> 6;
    const int wave = blockIdx.x * waves_per_block + wave_in_block;
    const int nwaves = gridDim.x * waves_per_block;
    const float sign = (lane == 0) ? -1.0f : 1.0f;  // Minkowski J
    float* __restrict__ grad = out + 1;

    float eacc = 0.0f;

    for (int e = wave; e < E; e += nwaves) {
        const int u = u_idx[e];
        const int v = v_idx[e];
        const float xu = x[(size_t)u * 64 + lane];
        const float xv = x[(size_t)v * 64 + lane];
        float p = xu * xv * sign;
        // 64-lane butterfly; result bitwise-identical across lanes
        #pragma unroll
        for (int off = 32; off >= 1; off >>= 1)
            p += __shfl_xor(p, off, 64);

        const float inner = fminf(p, -1.0f - 1e-7f);
        const float s = sqrtf(inner * inner - 1.0f);
        const float t = -inner + s;                 // dist = log(t)
        if (t < EXP_EPS) {                          // dist < EPS (wave-uniform branch)
            const float dist = __logf(t);
            const float delta = EPS_F - dist;
            eacc += delta * delta;
            const float factor = -(A_F / NUMNEG_F) * delta / (s + 1e-9f);
            // fully coalesced: 64 lanes x consecutive dwords = 256 B per atomic instr
            unsafeAtomicAdd(&grad[(size_t)u * 64 + lane], factor * xv * sign);
            unsafeAtomicAdd(&grad[(size_t)v * 64 + lane], factor * xu * sign);
        }
    }

    if (lane == 0 && eacc != 0.0f) {
        unsafeAtomicAdd(&out[0], eacc * (0.5f * A_F / NUMNEG_F));
    }
}

extern "C" void kernel_launch(void* const* d_in, const int* in_sizes, int n_in,
                              void* d_out, int out_size, void* d_ws, size_t ws_size,
                              hipStream_t stream) {
    const float* x     = (const float*)d_in[0];
    const int*   u_idx = (const int*)d_in[1];
    const int*   v_idx = (const int*)d_in[2];
    float* out = (float*)d_out;
    const int E = in_sizes[1];

    // d_out is poisoned with 0xAA before every timed launch; zero it (async, capture-safe)
    hipMemsetAsync(d_out, 0, (size_t)out_size * sizeof(float), stream);

    // grid-stride over edges, one wave (64 lanes) per edge
    const int blocks = 4096;  // 16384 waves, ~61 edges each
    grp_edge_kernel<<<blocks, 256, 0, stream>>>(x, u_idx, v_idx, out, E);
}